// Round 1
// baseline (74.388 us; speedup 1.0000x reference)
//
#include <hip/hip_runtime.h>
#include <stdint.h>

#define NN   4096
#define NE   131072
#define KIN  512
#define NH   8
#define NF   32
#define HF   256
#define SLOPE 0.2f

// ---------------------------------------------------------------------------
// ws layout:
//   [0, 2MB)            : adjacency bitmap, NN rows x 128 u32 words
//   [2MB, 6MB)          : g  [NN][HF] f32
//   [6MB, 6MB+128KB)    : el [NN][NH] f32
//   [6MB+128KB, +128KB) : er [NN][NH] f32
// ---------------------------------------------------------------------------

__global__ __launch_bounds__(256) void build_adj_k(const int* __restrict__ ei,
                                                   const float* __restrict__ mask,
                                                   unsigned* __restrict__ bitmap) {
  int k = blockIdx.x * 256 + threadIdx.x;
  if (k >= NE + NN) return;
  int s, d; float m;
  if (k < NE) { s = ei[k]; d = ei[NE + k]; m = mask[k]; }
  else        { s = k - NE; d = s; m = 1.0f; }   // diagonal forced to 1
  if (m != 0.0f) atomicOr(&bitmap[s * 128 + (d >> 5)], 1u << (d & 31));
}

// C[4096,256] = A[4096,512] @ B[512,256], f32 (no fp32 MFMA on CDNA4)
__global__ __launch_bounds__(256) void gemm_k(const float* __restrict__ A,
                                              const float* __restrict__ B,
                                              float* __restrict__ C) {
  __shared__ float As[16][64];  // [k][m]
  __shared__ float Bs[16][64];  // [k][n]
  const int t   = threadIdx.x;
  const int row0 = blockIdx.x * 64;
  const int col0 = blockIdx.y * 64;
  const int tr = t >> 4, tc = t & 15;
  const int arow = t >> 2, akq = (t & 3) << 2;
  const int bkk = t >> 4,  bnq = (t & 15) << 2;
  float acc[4][4] = {};
  for (int k0 = 0; k0 < KIN; k0 += 16) {
    float4 a4 = *(const float4*)&A[(size_t)(row0 + arow) * KIN + k0 + akq];
    float4 b4 = *(const float4*)&B[(size_t)(k0 + bkk) * HF + col0 + bnq];
    __syncthreads();  // protect previous iteration's LDS reads
    As[akq + 0][arow] = a4.x;
    As[akq + 1][arow] = a4.y;
    As[akq + 2][arow] = a4.z;
    As[akq + 3][arow] = a4.w;
    *(float4*)&Bs[bkk][bnq] = b4;
    __syncthreads();
#pragma unroll
    for (int kk = 0; kk < 16; ++kk) {
      float4 av = *(const float4*)&As[kk][tr << 2];
      float4 bv = *(const float4*)&Bs[kk][tc << 2];
      float a[4] = {av.x, av.y, av.z, av.w};
      float b[4] = {bv.x, bv.y, bv.z, bv.w};
#pragma unroll
      for (int i2 = 0; i2 < 4; ++i2)
#pragma unroll
        for (int j2 = 0; j2 < 4; ++j2) acc[i2][j2] += a[i2] * b[j2];
    }
  }
#pragma unroll
  for (int i2 = 0; i2 < 4; ++i2) {
    float4 v = make_float4(acc[i2][0], acc[i2][1], acc[i2][2], acc[i2][3]);
    *(float4*)&C[(size_t)(row0 + (tr << 2) + i2) * HF + col0 + (tc << 2)] = v;
  }
}

// el[i,h] = sum_f g[i,h,f]*Wa[f]; er[i,h] = sum_f g[i,h,f]*Wa[F+f]
__global__ __launch_bounds__(256) void el_er_k(const float* __restrict__ g,
                                               const float* __restrict__ Wa,
                                               float* __restrict__ el,
                                               float* __restrict__ er) {
  const int i = blockIdx.x;
  const int t = threadIdx.x;
  const int f = t & 31;
  float gv  = g[(size_t)i * HF + t];       // coalesced 1KB row read
  float pel = gv * Wa[f];
  float per = gv * Wa[32 + f];
#pragma unroll
  for (int m = 16; m >= 1; m >>= 1) {      // masks <32: stays within 32-lane group
    pel += __shfl_xor(pel, m);
    per += __shfl_xor(per, m);
  }
  if (f == 0) {
    int h = t >> 5;
    el[i * NH + h] = pel;
    er[i * NH + h] = per;
  }
}

// one block per row i; thread t owns output element (h=t>>5, f=t&31)
__global__ __launch_bounds__(256) void attn_k(const unsigned* __restrict__ bitmap,
                                              const float* __restrict__ g,
                                              const float* __restrict__ el_,
                                              const float* __restrict__ er_,
                                              float* __restrict__ out) {
  __shared__ unsigned short jl[NN];   // neighbor list (worst case full row)
  __shared__ int   wtot[4];
  __shared__ int   totalS;
  __shared__ float redm[4][NH];

  const int i = blockIdx.x;
  const int t = threadIdx.x;
  const int lane = t & 63;

  // --- expand bitmap row -> sorted neighbor list (deterministic) ---
  unsigned w = 0; int cnt = 0;
  if (t < 128) { w = bitmap[i * 128 + t]; cnt = __popc(w); }
  int incl = cnt;
#pragma unroll
  for (int d = 1; d < 64; d <<= 1) {
    int u = __shfl_up(incl, d);
    if (lane >= d) incl += u;
  }
  if (lane == 63) wtot[t >> 6] = incl;
  __syncthreads();
  int base = (t >= 64 && t < 128) ? wtot[0] : 0;
  if (t == 127) totalS = base + incl;
  if (t < 128) {
    int off = base + incl - cnt;
    unsigned ww = w;
    while (ww) {
      int b = __ffs(ww) - 1;
      jl[off++] = (unsigned short)(t * 32 + b);
      ww &= ww - 1;
    }
  }
  __syncthreads();
  const int total = totalS;

  // --- pass 1: per-head max of er over neighbors (lr is monotone) ---
  float mx[NH];
#pragma unroll
  for (int h = 0; h < NH; ++h) mx[h] = -1e30f;
  for (int k = t; k < total; k += 256) {
    int j = jl[k];
    const float4* p = (const float4*)&er_[(size_t)j * NH];
    float4 e0 = p[0], e1 = p[1];
    mx[0] = fmaxf(mx[0], e0.x); mx[1] = fmaxf(mx[1], e0.y);
    mx[2] = fmaxf(mx[2], e0.z); mx[3] = fmaxf(mx[3], e0.w);
    mx[4] = fmaxf(mx[4], e1.x); mx[5] = fmaxf(mx[5], e1.y);
    mx[6] = fmaxf(mx[6], e1.z); mx[7] = fmaxf(mx[7], e1.w);
  }
#pragma unroll
  for (int d = 32; d >= 1; d >>= 1)
#pragma unroll
    for (int h = 0; h < NH; ++h) mx[h] = fmaxf(mx[h], __shfl_xor(mx[h], d));
  if (lane == 0)
#pragma unroll
    for (int h = 0; h < NH; ++h) redm[t >> 6][h] = mx[h];
  __syncthreads();

  const int h = t >> 5;
  float maxer = fmaxf(fmaxf(redm[0][h], redm[1][h]), fmaxf(redm[2][h], redm[3][h]));
  float elh = el_[i * NH + h];
  float Me  = elh + maxer;
  Me = Me > 0.f ? Me : SLOPE * Me;   // lr(el + max er) == max over neighbors of lr

  // --- pass 2: softmax-weighted accumulation (deterministic order) ---
  float acc = 0.f, denom = 0.f;
  for (int k = 0; k < total; ++k) {
    int j = jl[k];
    float e  = elh + er_[(size_t)j * NH + h];   // broadcast within 32-lane group
    float lr = e > 0.f ? e : SLOPE * e;
    float wg = __expf(lr - Me);
    denom += wg;
    acc   += wg * g[(size_t)j * HF + t];        // coalesced 1KB row read
  }
  out[(size_t)i * HF + t] = acc / denom;
}

extern "C" void kernel_launch(void* const* d_in, const int* in_sizes, int n_in,
                              void* d_out, int out_size, void* d_ws, size_t ws_size,
                              hipStream_t stream) {
  const float* h      = (const float*)d_in[0];
  const int*   ei     = (const int*)d_in[1];
  const float* mask   = (const float*)d_in[2];
  const float* W_fc   = (const float*)d_in[3];
  const float* W_attn = (const float*)d_in[4];
  float* out = (float*)d_out;

  char* ws = (char*)d_ws;
  unsigned* bitmap = (unsigned*)ws;                               // 2 MB
  float* g  = (float*)(ws + (size_t)2 * 1024 * 1024);             // 4 MB
  float* el = (float*)(ws + (size_t)6 * 1024 * 1024);             // 128 KB
  float* er = (float*)(ws + (size_t)6 * 1024 * 1024 + 128 * 1024);// 128 KB

  hipMemsetAsync(bitmap, 0, (size_t)NN * 128 * 4, stream);
  build_adj_k<<<(NE + NN + 255) / 256, 256, 0, stream>>>(ei, mask, bitmap);
  dim3 ggrid(NN / 64, HF / 64);
  gemm_k<<<ggrid, 256, 0, stream>>>(h, W_fc, g);
  el_er_k<<<NN, 256, 0, stream>>>(g, W_attn, el, er);
  attn_k<<<NN, 256, 0, stream>>>(bitmap, g, el, er, out);
}

// Round 2
// 73.844 us; speedup vs baseline: 1.0074x; 1.0074x over previous
//
#include <hip/hip_runtime.h>
#include <stdint.h>

#define NN   4096
#define NE   131072
#define KIN  512
#define NH   8
#define NF   32
#define HF   256
#define SLOPE 0.2f

// ---------------------------------------------------------------------------
// ws layout:
//   [0, 2MB)            : adjacency bitmap, NN rows x 128 u32 words
//   [2MB, 6MB)          : g  [NN][HF] f32
//   [6MB, 6MB+128KB)    : el [NN][NH] f32
//   [6MB+128KB, +128KB) : er [NN][NH] f32
// ---------------------------------------------------------------------------

// custom clear: runtime's fillBuffer took 43.9us for 2MB (latency-bound grid);
// 512 blocks x 256 threads x float4 does it in ~3us.
__global__ __launch_bounds__(256) void clear_k(float4* __restrict__ p) {
  int i = blockIdx.x * 256 + threadIdx.x;
  p[i] = make_float4(0.f, 0.f, 0.f, 0.f);
}

__global__ __launch_bounds__(256) void build_adj_k(const int* __restrict__ ei,
                                                   const float* __restrict__ mask,
                                                   unsigned* __restrict__ bitmap) {
  int k = blockIdx.x * 256 + threadIdx.x;
  if (k >= NE + NN) return;
  int s, d; float m;
  if (k < NE) { s = ei[k]; d = ei[NE + k]; m = mask[k]; }
  else        { s = k - NE; d = s; m = 1.0f; }   // diagonal forced to 1
  if (m != 0.0f) atomicOr(&bitmap[s * 128 + (d >> 5)], 1u << (d & 31));
}

// C[4096,256] = A[4096,512] @ B[512,256], f32 (no fp32 MFMA on CDNA4)
__global__ __launch_bounds__(256) void gemm_k(const float* __restrict__ A,
                                              const float* __restrict__ B,
                                              float* __restrict__ C) {
  __shared__ float As[16][64];  // [k][m]
  __shared__ float Bs[16][64];  // [k][n]
  const int t   = threadIdx.x;
  const int row0 = blockIdx.x * 64;
  const int col0 = blockIdx.y * 64;
  const int tr = t >> 4, tc = t & 15;
  const int arow = t >> 2, akq = (t & 3) << 2;
  const int bkk = t >> 4,  bnq = (t & 15) << 2;
  float acc[4][4] = {};
  for (int k0 = 0; k0 < KIN; k0 += 16) {
    float4 a4 = *(const float4*)&A[(size_t)(row0 + arow) * KIN + k0 + akq];
    float4 b4 = *(const float4*)&B[(size_t)(k0 + bkk) * HF + col0 + bnq];
    __syncthreads();  // protect previous iteration's LDS reads
    As[akq + 0][arow] = a4.x;
    As[akq + 1][arow] = a4.y;
    As[akq + 2][arow] = a4.z;
    As[akq + 3][arow] = a4.w;
    *(float4*)&Bs[bkk][bnq] = b4;
    __syncthreads();
#pragma unroll
    for (int kk = 0; kk < 16; ++kk) {
      float4 av = *(const float4*)&As[kk][tr << 2];
      float4 bv = *(const float4*)&Bs[kk][tc << 2];
      float a[4] = {av.x, av.y, av.z, av.w};
      float b[4] = {bv.x, bv.y, bv.z, bv.w};
#pragma unroll
      for (int i2 = 0; i2 < 4; ++i2)
#pragma unroll
        for (int j2 = 0; j2 < 4; ++j2) acc[i2][j2] += a[i2] * b[j2];
    }
  }
#pragma unroll
  for (int i2 = 0; i2 < 4; ++i2) {
    float4 v = make_float4(acc[i2][0], acc[i2][1], acc[i2][2], acc[i2][3]);
    *(float4*)&C[(size_t)(row0 + (tr << 2) + i2) * HF + col0 + (tc << 2)] = v;
  }
}

// el[i,h] = sum_f g[i,h,f]*Wa[f]; er[i,h] = sum_f g[i,h,f]*Wa[F+f]
__global__ __launch_bounds__(256) void el_er_k(const float* __restrict__ g,
                                               const float* __restrict__ Wa,
                                               float* __restrict__ el,
                                               float* __restrict__ er) {
  const int i = blockIdx.x;
  const int t = threadIdx.x;
  const int f = t & 31;
  float gv  = g[(size_t)i * HF + t];       // coalesced 1KB row read
  float pel = gv * Wa[f];
  float per = gv * Wa[32 + f];
#pragma unroll
  for (int m = 16; m >= 1; m >>= 1) {      // masks <32: stays within 32-lane group
    pel += __shfl_xor(pel, m);
    per += __shfl_xor(per, m);
  }
  if (f == 0) {
    int h = t >> 5;
    el[i * NH + h] = pel;
    er[i * NH + h] = per;
  }
}

// one block per row i; thread t owns output element (h=t>>5, f=t&31)
__global__ __launch_bounds__(256) void attn_k(const unsigned* __restrict__ bitmap,
                                              const float* __restrict__ g,
                                              const float* __restrict__ el_,
                                              const float* __restrict__ er_,
                                              float* __restrict__ out) {
  __shared__ unsigned short jl[NN];   // neighbor list (worst case full row)
  __shared__ int   wtot[4];
  __shared__ int   totalS;
  __shared__ float redm[4][NH];

  const int i = blockIdx.x;
  const int t = threadIdx.x;
  const int lane = t & 63;

  // --- expand bitmap row -> sorted neighbor list (deterministic) ---
  unsigned w = 0; int cnt = 0;
  if (t < 128) { w = bitmap[i * 128 + t]; cnt = __popc(w); }
  int incl = cnt;
#pragma unroll
  for (int d = 1; d < 64; d <<= 1) {
    int u = __shfl_up(incl, d);
    if (lane >= d) incl += u;
  }
  if (lane == 63) wtot[t >> 6] = incl;
  __syncthreads();
  int base = (t >= 64 && t < 128) ? wtot[0] : 0;
  if (t == 127) totalS = base + incl;
  if (t < 128) {
    int off = base + incl - cnt;
    unsigned ww = w;
    while (ww) {
      int b = __ffs(ww) - 1;
      jl[off++] = (unsigned short)(t * 32 + b);
      ww &= ww - 1;
    }
  }
  __syncthreads();
  const int total = totalS;

  // --- pass 1: per-head max of er over neighbors (lr is monotone) ---
  float mx[NH];
#pragma unroll
  for (int h = 0; h < NH; ++h) mx[h] = -1e30f;
  for (int k = t; k < total; k += 256) {
    int j = jl[k];
    const float4* p = (const float4*)&er_[(size_t)j * NH];
    float4 e0 = p[0], e1 = p[1];
    mx[0] = fmaxf(mx[0], e0.x); mx[1] = fmaxf(mx[1], e0.y);
    mx[2] = fmaxf(mx[2], e0.z); mx[3] = fmaxf(mx[3], e0.w);
    mx[4] = fmaxf(mx[4], e1.x); mx[5] = fmaxf(mx[5], e1.y);
    mx[6] = fmaxf(mx[6], e1.z); mx[7] = fmaxf(mx[7], e1.w);
  }
#pragma unroll
  for (int d = 32; d >= 1; d >>= 1)
#pragma unroll
    for (int h = 0; h < NH; ++h) mx[h] = fmaxf(mx[h], __shfl_xor(mx[h], d));
  if (lane == 0)
#pragma unroll
    for (int h = 0; h < NH; ++h) redm[t >> 6][h] = mx[h];
  __syncthreads();

  const int h = t >> 5;
  float maxer = fmaxf(fmaxf(redm[0][h], redm[1][h]), fmaxf(redm[2][h], redm[3][h]));
  float elh = el_[i * NH + h];
  float Me  = elh + maxer;
  Me = Me > 0.f ? Me : SLOPE * Me;   // lr(el + max er) == max over neighbors of lr

  // --- pass 2: softmax-weighted accumulation (deterministic order) ---
  float acc = 0.f, denom = 0.f;
  for (int k = 0; k < total; ++k) {
    int j = jl[k];
    float e  = elh + er_[(size_t)j * NH + h];   // broadcast within 32-lane group
    float lr = e > 0.f ? e : SLOPE * e;
    float wg = __expf(lr - Me);
    denom += wg;
    acc   += wg * g[(size_t)j * HF + t];        // coalesced 1KB row read
  }
  out[(size_t)i * HF + t] = acc / denom;
}

extern "C" void kernel_launch(void* const* d_in, const int* in_sizes, int n_in,
                              void* d_out, int out_size, void* d_ws, size_t ws_size,
                              hipStream_t stream) {
  const float* h      = (const float*)d_in[0];
  const int*   ei     = (const int*)d_in[1];
  const float* mask   = (const float*)d_in[2];
  const float* W_fc   = (const float*)d_in[3];
  const float* W_attn = (const float*)d_in[4];
  float* out = (float*)d_out;

  char* ws = (char*)d_ws;
  unsigned* bitmap = (unsigned*)ws;                               // 2 MB
  float* g  = (float*)(ws + (size_t)2 * 1024 * 1024);             // 4 MB
  float* el = (float*)(ws + (size_t)6 * 1024 * 1024);             // 128 KB
  float* er = (float*)(ws + (size_t)6 * 1024 * 1024 + 128 * 1024);// 128 KB

  clear_k<<<512, 256, 0, stream>>>((float4*)bitmap);              // 2MB zero
  build_adj_k<<<(NE + NN + 255) / 256, 256, 0, stream>>>(ei, mask, bitmap);
  dim3 ggrid(NN / 64, HF / 64);
  gemm_k<<<ggrid, 256, 0, stream>>>(h, W_fc, g);
  el_er_k<<<NN, 256, 0, stream>>>(g, W_attn, el, er);
  attn_k<<<NN, 256, 0, stream>>>(bitmap, g, el, er, out);
}

// Round 3
// 49.679 us; speedup vs baseline: 1.4974x; 1.4864x over previous
//
#include <hip/hip_runtime.h>
#include <stdint.h>

#define NN   4096
#define NE   131072
#define KIN  512
#define NH   8
#define HF   256
#define SLOPE 0.2f

typedef __attribute__((ext_vector_type(8))) short bf16x8;
typedef __attribute__((ext_vector_type(4))) float f32x4;

// ---------------------------------------------------------------------------
// ws layout:
//   [0, 2MB)        : adjacency bitmap, NN rows x 128 u32 words
//   [2MB, 6MB)      : g  [NN][HF] f32
//   [6MB, +128KB)   : el [NN][NH] f32
//   [6.125MB,+128K) : er [NN][NH] f32
//   [6.25MB, +4MB)  : Abf [NN][KIN] bf16
//   [10.25MB,+256K) : Btbf [HF][KIN] bf16 (W_fc transposed)
// ---------------------------------------------------------------------------

__device__ __forceinline__ unsigned short f2bf(float x) {  // RTN f32->bf16
  unsigned u = __builtin_bit_cast(unsigned, x);
  u += 0x7FFFu + ((u >> 16) & 1u);
  return (unsigned short)(u >> 16);
}

__global__ __launch_bounds__(256) void clear_k(float4* __restrict__ p) {
  int i = blockIdx.x * 256 + threadIdx.x;
  p[i] = make_float4(0.f, 0.f, 0.f, 0.f);
}

__global__ __launch_bounds__(256) void build_adj_k(const int* __restrict__ ei,
                                                   const float* __restrict__ mask,
                                                   unsigned* __restrict__ bitmap) {
  int k = blockIdx.x * 256 + threadIdx.x;
  if (k >= NE + NN) return;
  int s, d; float m;
  if (k < NE) { s = ei[k]; d = ei[NE + k]; m = mask[k]; }
  else        { s = k - NE; d = s; m = 1.0f; }   // diagonal forced to 1
  if (m != 0.0f) atomicOr(&bitmap[s * 128 + (d >> 5)], 1u << (d & 31));
}

// blocks 0..2047: h f32 -> Abf bf16 (straight). blocks 2048..2175: W_fc -> Bt bf16 (32x32 tile transpose)
__global__ __launch_bounds__(256) void convert_k(const float* __restrict__ A,
                                                 const float* __restrict__ B,
                                                 unsigned short* __restrict__ Abf,
                                                 unsigned short* __restrict__ Btbf) {
  int b = blockIdx.x, t = threadIdx.x;
  if (b < 2048) {
    size_t idx = ((size_t)b * 256 + t) * 4;
    float4 v = *(const float4*)&A[idx];
    ushort4 o;
    o.x = f2bf(v.x); o.y = f2bf(v.y); o.z = f2bf(v.z); o.w = f2bf(v.w);
    *(ushort4*)&Abf[idx] = o;
  } else {
    __shared__ float tile[32][33];
    int bb = b - 2048;
    int k0 = (bb >> 3) * 32, n0 = (bb & 7) * 32;
    int lr = t >> 3, lc = (t & 7) * 4;
    float4 v = *(const float4*)&B[(size_t)(k0 + lr) * HF + n0 + lc];
    tile[lr][lc] = v.x; tile[lr][lc + 1] = v.y; tile[lr][lc + 2] = v.z; tile[lr][lc + 3] = v.w;
    __syncthreads();
    ushort4 o;
    o.x = f2bf(tile[lc + 0][lr]); o.y = f2bf(tile[lc + 1][lr]);
    o.z = f2bf(tile[lc + 2][lr]); o.w = f2bf(tile[lc + 3][lr]);
    *(ushort4*)&Btbf[(size_t)(n0 + lr) * KIN + k0 + lc] = o;
  }
}

// C[4096,256] = Abf @ Btbf^T, bf16 MFMA 16x16x32, 64x64 tile, BK=32, dbuf LDS.
// LDS k-chunk swizzle: slot = (kc ^ ((row>>1)&3)) & 3  (2-way banks = free);
// global_load_lds writes linearly, so the SOURCE address is pre-swizzled (rule #21).
__global__ __launch_bounds__(256) void gemm_mfma_k(const unsigned short* __restrict__ A,
                                                   const unsigned short* __restrict__ Bt,
                                                   float* __restrict__ C) {
  __shared__ unsigned short smem[2][4096];  // per buf: A rows 0-63 @[0], B rows 0-63 @[2048] (64x32 bf16 each)
  const int t = threadIdx.x;
  const int w = t >> 6;          // wave 0..3
  const int l = t & 63;
  const int row0 = blockIdx.x * 64;
  const int col0 = blockIdx.y * 64;
  const int wr = w >> 1, wc = w & 1;

  // staging: inst w covers rows w*16..w*16+15; lane l -> row w*16+(l>>2), k-chunk (l&3)^((l>>3)&3)
  const int srow = l >> 2;
  const int skc  = (l & 3) ^ ((l >> 3) & 3);
  const unsigned short* gA = &A[(size_t)(row0 + w * 16 + srow) * KIN + skc * 8];
  const unsigned short* gB = &Bt[(size_t)(col0 + w * 16 + srow) * KIN + skc * 8];

  f32x4 acc[2][2] = {};

#define STAGE(bf, ks)                                                                              \
  do {                                                                                             \
    __builtin_amdgcn_global_load_lds(                                                              \
        (const __attribute__((address_space(1))) unsigned int*)(gA + (ks) * 32),                   \
        (__attribute__((address_space(3))) unsigned int*)(&smem[bf][w * 512]), 16, 0, 0);          \
    __builtin_amdgcn_global_load_lds(                                                              \
        (const __attribute__((address_space(1))) unsigned int*)(gB + (ks) * 32),                   \
        (__attribute__((address_space(3))) unsigned int*)(&smem[bf][2048 + w * 512]), 16, 0, 0);   \
  } while (0)

  STAGE(0, 0);
  __syncthreads();
  const int lrow = l & 15, kg = l >> 4;
  for (int ks = 0; ks < 16; ++ks) {
    const int bf = ks & 1;
    if (ks + 1 < 16) STAGE(bf ^ 1, ks + 1);
    bf16x8 a[2], bb[2];
#pragma unroll
    for (int r = 0; r < 2; ++r) {
      int row = wr * 32 + r * 16 + lrow;
      int slot = (kg ^ (row >> 1)) & 3;
      a[r] = *(const bf16x8*)&smem[bf][row * 32 + slot * 8];
    }
#pragma unroll
    for (int c = 0; c < 2; ++c) {
      int n = wc * 32 + c * 16 + lrow;
      int slot = (kg ^ (n >> 1)) & 3;
      bb[c] = *(const bf16x8*)&smem[bf][2048 + n * 32 + slot * 8];
    }
    acc[0][0] = __builtin_amdgcn_mfma_f32_16x16x32_bf16(a[0], bb[0], acc[0][0], 0, 0, 0);
    acc[0][1] = __builtin_amdgcn_mfma_f32_16x16x32_bf16(a[0], bb[1], acc[0][1], 0, 0, 0);
    acc[1][0] = __builtin_amdgcn_mfma_f32_16x16x32_bf16(a[1], bb[0], acc[1][0], 0, 0, 0);
    acc[1][1] = __builtin_amdgcn_mfma_f32_16x16x32_bf16(a[1], bb[1], acc[1][1], 0, 0, 0);
    __syncthreads();
  }
#undef STAGE

  // C/D layout: col=lane&15, row=(lane>>4)*4+q  [m89-verified]
  const int crow = (l >> 4) * 4, ccol = l & 15;
#pragma unroll
  for (int r = 0; r < 2; ++r)
#pragma unroll
    for (int c = 0; c < 2; ++c) {
      int gr = row0 + wr * 32 + r * 16 + crow;
      int gc = col0 + wc * 32 + c * 16 + ccol;
#pragma unroll
      for (int q = 0; q < 4; ++q) C[(size_t)(gr + q) * HF + gc] = acc[r][c][q];
    }
}

// el[i,h] = sum_f g[i,h,f]*Wa[f]; er[i,h] = sum_f g[i,h,f]*Wa[F+f]
__global__ __launch_bounds__(256) void el_er_k(const float* __restrict__ g,
                                               const float* __restrict__ Wa,
                                               float* __restrict__ el,
                                               float* __restrict__ er) {
  const int i = blockIdx.x;
  const int t = threadIdx.x;
  const int f = t & 31;
  float gv  = g[(size_t)i * HF + t];
  float pel = gv * Wa[f];
  float per = gv * Wa[32 + f];
#pragma unroll
  for (int m = 16; m >= 1; m >>= 1) {
    pel += __shfl_xor(pel, m);
    per += __shfl_xor(per, m);
  }
  if (f == 0) {
    int h = t >> 5;
    el[i * NH + h] = pel;
    er[i * NH + h] = per;
  }
}

// one block per row i; thread t owns output element (h=t>>5, f=t&31).
// no max-subtraction: |e| <= ~10 so exp(e) is f32-safe; softmax shift-invariant.
__global__ __launch_bounds__(256) void attn_k(const unsigned* __restrict__ bitmap,
                                              const float* __restrict__ g,
                                              const float* __restrict__ el_,
                                              const float* __restrict__ er_,
                                              float* __restrict__ out) {
  __shared__ unsigned short jl[NN];
  __shared__ int wtot[4];
  __shared__ int totalS;

  const int i = blockIdx.x;
  const int t = threadIdx.x;
  const int lane = t & 63;

  // expand bitmap row -> sorted neighbor list (deterministic)
  unsigned w = 0; int cnt = 0;
  if (t < 128) { w = bitmap[i * 128 + t]; cnt = __popc(w); }
  int incl = cnt;
#pragma unroll
  for (int d = 1; d < 64; d <<= 1) {
    int u = __shfl_up(incl, d);
    if (lane >= d) incl += u;
  }
  if (lane == 63) wtot[t >> 6] = incl;
  __syncthreads();
  int base = (t >= 64 && t < 128) ? wtot[0] : 0;
  if (t == 127) totalS = base + incl;
  if (t < 128) {
    int off = base + incl - cnt;
    unsigned ww = w;
    while (ww) {
      int b = __ffs(ww) - 1;
      jl[off++] = (unsigned short)(t * 32 + b);
      ww &= ww - 1;
    }
  }
  __syncthreads();
  const int total = totalS;

  const int h = t >> 5;
  const float elh = el_[i * NH + h];
  float acc = 0.f, denom = 0.f;
  for (int k = 0; k < total; ++k) {
    int j = jl[k];
    float e  = elh + er_[(size_t)j * NH + h];
    float lr = e > 0.f ? e : SLOPE * e;
    float wg = __expf(lr);
    denom += wg;
    acc   += wg * g[(size_t)j * HF + t];
  }
  out[(size_t)i * HF + t] = acc / denom;
}

extern "C" void kernel_launch(void* const* d_in, const int* in_sizes, int n_in,
                              void* d_out, int out_size, void* d_ws, size_t ws_size,
                              hipStream_t stream) {
  const float* h      = (const float*)d_in[0];
  const int*   ei     = (const int*)d_in[1];
  const float* mask   = (const float*)d_in[2];
  const float* W_fc   = (const float*)d_in[3];
  const float* W_attn = (const float*)d_in[4];
  float* out = (float*)d_out;

  char* ws = (char*)d_ws;
  unsigned* bitmap      = (unsigned*)ws;                                  // 2 MB
  float* g              = (float*)(ws + (size_t)2 * 1024 * 1024);         // 4 MB
  float* el             = (float*)(ws + (size_t)6 * 1024 * 1024);         // 128 KB
  float* er             = (float*)(ws + (size_t)6 * 1024 * 1024 + 128 * 1024);
  unsigned short* Abf   = (unsigned short*)(ws + (size_t)6 * 1024 * 1024 + 256 * 1024);  // 4 MB
  unsigned short* Btbf  = (unsigned short*)(ws + (size_t)10 * 1024 * 1024 + 256 * 1024); // 256 KB

  clear_k<<<512, 256, 0, stream>>>((float4*)bitmap);
  build_adj_k<<<(NE + NN + 255) / 256, 256, 0, stream>>>(ei, mask, bitmap);
  convert_k<<<2048 + 128, 256, 0, stream>>>(h, W_fc, Abf, Btbf);
  dim3 ggrid(NN / 64, HF / 64);
  gemm_mfma_k<<<ggrid, 256, 0, stream>>>(Abf, Btbf, g);
  el_er_k<<<NN, 256, 0, stream>>>(g, W_attn, el, er);
  attn_k<<<NN, 256, 0, stream>>>(bitmap, g, el, er, out);
}

// Round 4
// 39.257 us; speedup vs baseline: 1.8949x; 1.2655x over previous
//
#include <hip/hip_runtime.h>
#include <stdint.h>

#define NN   4096
#define NE   131072
#define KIN  512
#define NH   8
#define HF   256
#define SLOPE 0.2f

typedef __attribute__((ext_vector_type(8))) short bf16x8;
typedef __attribute__((ext_vector_type(4))) float f32x4;

// ---------------------------------------------------------------------------
// ws layout:
//   [0, 2MB)       : adjacency bitmap, NN rows x 128 u32 words
//   [2MB, 4MB)     : g   [NN][HF] bf16
//   [4MB, +128KB)  : el  [NN][NH] f32
//   [4.125MB,+128K): er  [NN][NH] f32
//   [4.25MB, +4MB) : Abf [NN][KIN] bf16
//   [8.25MB,+256K) : Btbf [HF][KIN] bf16 (W_fc transposed)
// ---------------------------------------------------------------------------

__device__ __forceinline__ unsigned short f2bf(float x) {  // RTN f32->bf16
  unsigned u = __builtin_bit_cast(unsigned, x);
  u += 0x7FFFu + ((u >> 16) & 1u);
  return (unsigned short)(u >> 16);
}
__device__ __forceinline__ float bf2f(unsigned short x) {
  unsigned u = ((unsigned)x) << 16;
  return __builtin_bit_cast(float, u);
}

// K1: blocks 0..511 clear bitmap; 512..2559 convert h->bf16; 2560..2687 W_fc -> B^T bf16
__global__ __launch_bounds__(256) void prep_k(const float* __restrict__ A,
                                              const float* __restrict__ B,
                                              unsigned* __restrict__ bitmap,
                                              unsigned short* __restrict__ Abf,
                                              unsigned short* __restrict__ Btbf) {
  __shared__ float tile[32][33];
  const int b = blockIdx.x, t = threadIdx.x;
  if (b < 512) {
    ((float4*)bitmap)[b * 256 + t] = make_float4(0.f, 0.f, 0.f, 0.f);
  } else if (b < 2560) {
    size_t idx = ((size_t)(b - 512) * 256 + t) * 4;
    float4 v = *(const float4*)&A[idx];
    ushort4 o;
    o.x = f2bf(v.x); o.y = f2bf(v.y); o.z = f2bf(v.z); o.w = f2bf(v.w);
    *(ushort4*)&Abf[idx] = o;
  } else {
    int bb = b - 2560;
    int k0 = (bb >> 3) * 32, n0 = (bb & 7) * 32;
    int lr = t >> 3, lc = (t & 7) * 4;
    float4 v = *(const float4*)&B[(size_t)(k0 + lr) * HF + n0 + lc];
    tile[lr][lc] = v.x; tile[lr][lc + 1] = v.y; tile[lr][lc + 2] = v.z; tile[lr][lc + 3] = v.w;
    __syncthreads();
    ushort4 o;
    o.x = f2bf(tile[lc + 0][lr]); o.y = f2bf(tile[lc + 1][lr]);
    o.z = f2bf(tile[lc + 2][lr]); o.w = f2bf(tile[lc + 3][lr]);
    *(ushort4*)&Btbf[(size_t)(n0 + lr) * KIN + k0 + lc] = o;
  }
}

// K2: blocks 0..255 = 64x64 MFMA GEMM tile (BK=64, dbuf, el/er fused epilogue);
//     blocks 256..783 = build_adj (needs only K1's clear).
__global__ __launch_bounds__(256) void gemm_adj_k(const unsigned short* __restrict__ A,
                                                  const unsigned short* __restrict__ Bt,
                                                  const float* __restrict__ Wa,
                                                  unsigned short* __restrict__ gbf,
                                                  float* __restrict__ el,
                                                  float* __restrict__ er,
                                                  const int* __restrict__ ei,
                                                  const float* __restrict__ mask,
                                                  unsigned* __restrict__ bitmap) {
  __shared__ unsigned short smem[2][8192];  // per buf: A 64x64 bf16 @[0], B 64x64 @[4096]
  const int bx = blockIdx.x, t = threadIdx.x;
  if (bx >= 256) {  // ---- build_adj ----
    int k = (bx - 256) * 256 + t;
    if (k < NE + NN) {
      int s, d; float m;
      if (k < NE) { s = ei[k]; d = ei[NE + k]; m = mask[k]; }
      else        { s = k - NE; d = s; m = 1.0f; }   // diagonal forced to 1
      if (m != 0.0f) atomicOr(&bitmap[s * 128 + (d >> 5)], 1u << (d & 31));
    }
    return;
  }
  // ---- gemm ----
  const int gx = bx & 63, gy = bx >> 6;
  const int row0 = gx * 64, col0 = gy * 64;
  const int w = t >> 6, l = t & 63;
  const int wr = w >> 1, wc = w & 1;

  // staging: LDS linear dest (wave-uniform base + lane*16B); source pre-swizzled
  // row = p*32 + (t>>3), slot = t&7 holds k-chunk (t&7)^(row&7)
  const int srow = t >> 3;
  const int schunk = (t & 7) ^ (srow & 7);
  const unsigned short* gA0 = &A[(size_t)(row0 + srow) * KIN + schunk * 8];
  const unsigned short* gA1 = &A[(size_t)(row0 + 32 + srow) * KIN + schunk * 8];
  const unsigned short* gB0 = &Bt[(size_t)(col0 + srow) * KIN + schunk * 8];
  const unsigned short* gB1 = &Bt[(size_t)(col0 + 32 + srow) * KIN + schunk * 8];

#define STAGE(bf, ks)                                                                              \
  do {                                                                                             \
    __builtin_amdgcn_global_load_lds(                                                              \
        (const __attribute__((address_space(1))) unsigned int*)(gA0 + (size_t)(ks) * 64),          \
        (__attribute__((address_space(3))) unsigned int*)(&smem[bf][w * 512]), 16, 0, 0);          \
    __builtin_amdgcn_global_load_lds(                                                              \
        (const __attribute__((address_space(1))) unsigned int*)(gA1 + (size_t)(ks) * 64),          \
        (__attribute__((address_space(3))) unsigned int*)(&smem[bf][2048 + w * 512]), 16, 0, 0);   \
    __builtin_amdgcn_global_load_lds(                                                              \
        (const __attribute__((address_space(1))) unsigned int*)(gB0 + (size_t)(ks) * 64),          \
        (__attribute__((address_space(3))) unsigned int*)(&smem[bf][4096 + w * 512]), 16, 0, 0);   \
    __builtin_amdgcn_global_load_lds(                                                              \
        (const __attribute__((address_space(1))) unsigned int*)(gB1 + (size_t)(ks) * 64),          \
        (__attribute__((address_space(3))) unsigned int*)(&smem[bf][6144 + w * 512]), 16, 0, 0);   \
  } while (0)

  f32x4 acc[2][2] = {};
  STAGE(0, 0);
  __syncthreads();

  const int lrow = l & 15, kg = l >> 4;
  for (int ks = 0; ks < 8; ++ks) {
    const int bf = ks & 1;
    if (ks < 7) STAGE(bf ^ 1, ks + 1);
    bf16x8 af[2][2], bg[2][2];
#pragma unroll
    for (int r = 0; r < 2; ++r) {
      int ar = wr * 32 + r * 16 + lrow;
#pragma unroll
      for (int s = 0; s < 2; ++s)
        af[r][s] = *(const bf16x8*)&smem[bf][ar * 64 + (((s * 4 + kg) ^ (ar & 7)) << 3)];
    }
#pragma unroll
    for (int c = 0; c < 2; ++c) {
      int br = wc * 32 + c * 16 + lrow;
#pragma unroll
      for (int s = 0; s < 2; ++s)
        bg[c][s] = *(const bf16x8*)&smem[bf][4096 + br * 64 + (((s * 4 + kg) ^ (br & 7)) << 3)];
    }
#pragma unroll
    for (int s = 0; s < 2; ++s) {
      acc[0][0] = __builtin_amdgcn_mfma_f32_16x16x32_bf16(af[0][s], bg[0][s], acc[0][0], 0, 0, 0);
      acc[0][1] = __builtin_amdgcn_mfma_f32_16x16x32_bf16(af[0][s], bg[1][s], acc[0][1], 0, 0, 0);
      acc[1][0] = __builtin_amdgcn_mfma_f32_16x16x32_bf16(af[1][s], bg[0][s], acc[1][0], 0, 0, 0);
      acc[1][1] = __builtin_amdgcn_mfma_f32_16x16x32_bf16(af[1][s], bg[1][s], acc[1][1], 0, 0, 0);
    }
    __syncthreads();
  }
#undef STAGE

  // C/D layout: col=lane&15, row=(lane>>4)*4+q  [m89-verified]
  const int crow = (l >> 4) * 4, ccol = l & 15;
#pragma unroll
  for (int r = 0; r < 2; ++r)
#pragma unroll
    for (int c = 0; c < 2; ++c) {
      int gc = col0 + wc * 32 + c * 16 + ccol;
#pragma unroll
      for (int q = 0; q < 4; ++q) {
        int gr = row0 + wr * 32 + r * 16 + crow + q;
        gbf[(size_t)gr * HF + gc] = f2bf(acc[r][c][q]);
      }
    }

  // fused el/er: head = gy*2+wc lives wholly in this block; f = c*16+ccol
  const int head = (gy << 1) + wc;
  const float wal0 = Wa[ccol], wal1 = Wa[ccol + 16];
  const float war0 = Wa[32 + ccol], war1 = Wa[48 + ccol];
#pragma unroll
  for (int r = 0; r < 2; ++r)
#pragma unroll
    for (int q = 0; q < 4; ++q) {
      float pel = acc[r][0][q] * wal0 + acc[r][1][q] * wal1;
      float per = acc[r][0][q] * war0 + acc[r][1][q] * war1;
#pragma unroll
      for (int m = 8; m >= 1; m >>= 1) {   // reduce over 16 ccol lanes
        pel += __shfl_xor(pel, m);
        per += __shfl_xor(per, m);
      }
      if (ccol == 0) {
        int row = row0 + wr * 32 + r * 16 + crow + q;
        el[row * NH + head] = pel;
        er[row * NH + head] = per;
      }
    }
}

// K3: one block per row i; thread t owns output element (h=t>>5, f=t&31).
// no max-subtraction: |e| small so exp(e) f32-safe; softmax shift-invariant.
__global__ __launch_bounds__(256) void attn_k(const unsigned* __restrict__ bitmap,
                                              const unsigned short* __restrict__ gbf,
                                              const float* __restrict__ el_,
                                              const float* __restrict__ er_,
                                              float* __restrict__ out) {
  __shared__ unsigned short jl[NN];
  __shared__ int wtot[4];
  __shared__ int totalS;

  const int i = blockIdx.x;
  const int t = threadIdx.x;
  const int lane = t & 63;

  // expand bitmap row -> sorted neighbor list (deterministic)
  unsigned w = 0; int cnt = 0;
  if (t < 128) { w = bitmap[i * 128 + t]; cnt = __popc(w); }
  int incl = cnt;
#pragma unroll
  for (int d = 1; d < 64; d <<= 1) {
    int u = __shfl_up(incl, d);
    if (lane >= d) incl += u;
  }
  if (lane == 63) wtot[t >> 6] = incl;
  __syncthreads();
  int base = (t >= 64 && t < 128) ? wtot[0] : 0;
  if (t == 127) totalS = base + incl;
  if (t < 128) {
    int off = base + incl - cnt;
    unsigned ww = w;
    while (ww) {
      int b = __ffs(ww) - 1;
      jl[off++] = (unsigned short)(t * 32 + b);
      ww &= ww - 1;
    }
  }
  __syncthreads();
  const int total = totalS;

  const int h = t >> 5;
  const float elh = el_[i * NH + h];
  float acc0 = 0.f, den0 = 0.f, acc1 = 0.f, den1 = 0.f;
  int k = 0;
  for (; k + 2 <= total; k += 2) {          // 2-way unroll for MLP
    int j0 = jl[k], j1 = jl[k + 1];
    float e0 = elh + er_[(size_t)j0 * NH + h];
    float e1 = elh + er_[(size_t)j1 * NH + h];
    float g0 = bf2f(gbf[(size_t)j0 * HF + t]);
    float g1 = bf2f(gbf[(size_t)j1 * HF + t]);
    float l0 = e0 > 0.f ? e0 : SLOPE * e0;
    float l1 = e1 > 0.f ? e1 : SLOPE * e1;
    float w0 = __expf(l0), w1 = __expf(l1);
    den0 += w0; den1 += w1;
    acc0 += w0 * g0; acc1 += w1 * g1;
  }
  if (k < total) {
    int j0 = jl[k];
    float e0 = elh + er_[(size_t)j0 * NH + h];
    float g0 = bf2f(gbf[(size_t)j0 * HF + t]);
    float l0 = e0 > 0.f ? e0 : SLOPE * e0;
    float w0 = __expf(l0);
    den0 += w0; acc0 += w0 * g0;
  }
  out[(size_t)i * HF + t] = (acc0 + acc1) / (den0 + den1);
}

extern "C" void kernel_launch(void* const* d_in, const int* in_sizes, int n_in,
                              void* d_out, int out_size, void* d_ws, size_t ws_size,
                              hipStream_t stream) {
  const float* h      = (const float*)d_in[0];
  const int*   ei     = (const int*)d_in[1];
  const float* mask   = (const float*)d_in[2];
  const float* W_fc   = (const float*)d_in[3];
  const float* W_attn = (const float*)d_in[4];
  float* out = (float*)d_out;

  char* ws = (char*)d_ws;
  unsigned* bitmap      = (unsigned*)ws;                                          // 2 MB
  unsigned short* gbf   = (unsigned short*)(ws + (size_t)2 * 1024 * 1024);        // 2 MB
  float* el             = (float*)(ws + (size_t)4 * 1024 * 1024);                 // 128 KB
  float* er             = (float*)(ws + (size_t)4 * 1024 * 1024 + 128 * 1024);    // 128 KB
  unsigned short* Abf   = (unsigned short*)(ws + (size_t)4 * 1024 * 1024 + 256 * 1024);  // 4 MB
  unsigned short* Btbf  = (unsigned short*)(ws + (size_t)8 * 1024 * 1024 + 256 * 1024);  // 256 KB

  prep_k<<<2688, 256, 0, stream>>>(h, W_fc, bitmap, Abf, Btbf);
  gemm_adj_k<<<256 + 528, 256, 0, stream>>>(Abf, Btbf, W_attn, gbf, el, er, ei, mask, bitmap);
  attn_k<<<NN, 256, 0, stream>>>(bitmap, gbf, el, er, out);
}